// Round 1
// 1060.241 us; speedup vs baseline: 1.1047x; 1.1047x over previous
//
#include <hip/hip_runtime.h>
#include <hip/hip_bf16.h>
#include <math.h>

#define N_SEQ 1024
#define CS 384
#define CZ 128
#define NH 16
#define CH 24
#define HC 384

typedef float  floatx4 __attribute__((ext_vector_type(4)));
typedef short  shortx8 __attribute__((ext_vector_type(8)));
typedef unsigned int uintx4 __attribute__((ext_vector_type(4)));

__device__ __forceinline__ unsigned short f2bf(float f){
  union { float fv; unsigned u; } c; c.fv = f;
  unsigned u = c.u;
  return (unsigned short)((u + 0x7fffu + ((u >> 16) & 1u)) >> 16);
}
__device__ __forceinline__ float bf2f(unsigned short s){
  union { unsigned u; float fv; } c; c.u = ((unsigned)s) << 16; return c.fv;
}
__device__ __forceinline__ float bf_lo(unsigned u){
  union { unsigned uu; float f; } c; c.uu = u << 16; return c.f;
}
__device__ __forceinline__ float bf_hi(unsigned u){
  union { unsigned uu; float f; } c; c.uu = u & 0xffff0000u; return c.f;
}
__device__ __forceinline__ float sigmoidf_(float x){ return 1.f / (1.f + __expf(-x)); }

// ---------------- bias unit: one 16384-grid-equivalent block of the old bias kernel.
// Works with nthr = 256 or 384 (waves >= 4 idle through compute, help in epilogue).
// ob must point to >= 16*65 floats of shared memory.
__device__ __forceinline__ void bias_unit(int u, int tid, int nthr,
    const float* __restrict__ z, const float* __restrict__ lnb_w,
    const float* __restrict__ lnb_b, const float* __restrict__ wb,
    unsigned short* __restrict__ bias, float (*ob)[65])
{
  int i    = u >> 4;
  int j0   = (u & 15) * 64;
  int wave = tid >> 6;
  int lane = tid & 63;

  if (wave < 4){
    int m = lane & 15;   // A-row (pair) for loads; also D-col (head) in epilogue
    int q = lane >> 4;   // quad
    int jbase = j0 + wave * 16;

    shortx8 bfrag[4];
    float sumw = 0.f, sumb = 0.f;
    #pragma unroll
    for (int s = 0; s < 4; ++s){
      #pragma unroll
      for (int jj = 0; jj < 8; ++jj){
        int c = q*8 + jj + 32*s;
        float lw = lnb_w[c];
        float lb = lnb_b[c];
        float w  = wb[c*NH + m];
        bfrag[s][jj] = (short)f2bf(lw * w);
        sumw += lw * w;
        sumb += lb * w;
      }
    }
    sumw += __shfl_xor(sumw, 16); sumw += __shfl_xor(sumw, 32);
    sumb += __shfl_xor(sumb, 16); sumb += __shfl_xor(sumb, 32);

    const float* zrow = z + ((size_t)i * N_SEQ + (size_t)(jbase + m)) * CZ;
    floatx4 acc = {0.f, 0.f, 0.f, 0.f};
    float sum = 0.f, sq = 0.f;
    #pragma unroll
    for (int s = 0; s < 4; ++s){
      floatx4 z0 = *(const floatx4*)(zrow + q*8 + 32*s);
      floatx4 z1 = *(const floatx4*)(zrow + q*8 + 32*s + 4);
      shortx8 af;
      #pragma unroll
      for (int e = 0; e < 4; ++e){
        sum += z0[e]; sq += z0[e]*z0[e];
        sum += z1[e]; sq += z1[e]*z1[e];
        af[e]   = (short)f2bf(z0[e]);
        af[e+4] = (short)f2bf(z1[e]);
      }
      acc = __builtin_amdgcn_mfma_f32_16x16x32_bf16(af, bfrag[s], acc, 0, 0, 0);
    }
    sum += __shfl_xor(sum, 16); sum += __shfl_xor(sum, 32);
    sq  += __shfl_xor(sq , 16); sq  += __shfl_xor(sq , 32);
    float mean = sum * (1.f/CZ);
    float var  = sq  * (1.f/CZ) - mean*mean;
    float rstd = rsqrtf(var + 1e-5f);

    #pragma unroll
    for (int r = 0; r < 4; ++r){
      int row = q*4 + r;
      float mr = __shfl(mean, row);
      float rr = __shfl(rstd, row);
      ob[m][wave*16 + row] = rr * (acc[r] - mr * sumw) + sumb;
    }
  }
  __syncthreads();
  size_t base = (size_t)i * N_SEQ + j0;
  for (int idx = tid; idx < NH*64; idx += nthr){
    int hh = idx >> 6;
    int jj = idx & 63;
    bias[(size_t)hh * ((size_t)N_SEQ*N_SEQ) + base + jj] = f2bf(ob[hh][jj]);
  }
}

// ---------------- K1: LayerNorm (2 rows/block, 256 thr) + bias slice ----------------
#define LN_BLOCKS 512
#define NB1 3072
__global__ __launch_bounds__(256) void ln_bias_kernel(
    const float* __restrict__ a_i, const float* __restrict__ s_i,
    const float* __restrict__ lns_w,
    float* __restrict__ a_ln, float* __restrict__ s_ln,
    const float* __restrict__ z, const float* __restrict__ lnb_w,
    const float* __restrict__ lnb_b, const float* __restrict__ wb,
    unsigned short* __restrict__ biasw)
{
  __shared__ float ob[NH][65];
  if (blockIdx.x >= LN_BLOCKS){
    bias_unit(blockIdx.x - LN_BLOCKS, threadIdx.x, 256, z, lnb_w, lnb_b, wb, biasw, ob);
    return;
  }
  float* red = &ob[0][0];   // reuse 16 floats of the shared buffer
  int t    = threadIdx.x;
  int half = t >> 7;        // which of the 2 rows
  int tl   = t & 127;
  int row  = blockIdx.x*2 + half;
  float av[3], sv[3];
  float sa = 0.f, qa = 0.f, ss = 0.f, qs = 0.f;
  #pragma unroll
  for (int e = 0; e < 3; ++e){
    int c = tl + 128*e;
    float a = a_i[(size_t)row*CS + c];
    float s = s_i[(size_t)row*CS + c];
    av[e] = a; sv[e] = s;
    sa += a; qa += a*a; ss += s; qs += s*s;
  }
  #pragma unroll
  for (int off = 1; off < 64; off <<= 1){
    sa += __shfl_xor(sa, off);
    qa += __shfl_xor(qa, off);
    ss += __shfl_xor(ss, off);
    qs += __shfl_xor(qs, off);
  }
  if ((t & 63) == 0){
    int w = t >> 6;
    red[w*4+0] = sa; red[w*4+1] = qa; red[w*4+2] = ss; red[w*4+3] = qs;
  }
  __syncthreads();
  const float inv = 1.f / CS;
  int wb0 = half*2;
  float Sa = red[wb0*4+0] + red[(wb0+1)*4+0];
  float Qa = red[wb0*4+1] + red[(wb0+1)*4+1];
  float Ss = red[wb0*4+2] + red[(wb0+1)*4+2];
  float Qs = red[wb0*4+3] + red[(wb0+1)*4+3];
  float ma = Sa*inv, va = Qa*inv - ma*ma, ra = rsqrtf(va + 1e-5f);
  float ms = Ss*inv, vs = Qs*inv - ms*ms, rs = rsqrtf(vs + 1e-5f);
  #pragma unroll
  for (int e = 0; e < 3; ++e){
    int c = tl + 128*e;
    a_ln[(size_t)row*CS + c] = (av[e] - ma) * ra;
    s_ln[(size_t)row*CS + c] = (sv[e] - ms) * rs * lns_w[c];
  }
}

// ---------------- K2: AdaLN gemm (256 blocks, 384 thr) + bias slice ----------------
#define NB2 6656
__global__ __launch_bounds__(384) void adaln_bias_kernel(
    const float* __restrict__ X, const float* __restrict__ W1,
    const float* __restrict__ B1, const float* __restrict__ W2,
    const float* __restrict__ extra, float* __restrict__ OUT,
    const float* __restrict__ z, const float* __restrict__ lnb_w,
    const float* __restrict__ lnb_b, const float* __restrict__ wb,
    unsigned short* __restrict__ biasw)
{
  __shared__ float xl[4][CS];
  if (blockIdx.x >= 256){
    float (*ob)[65] = reinterpret_cast<float(*)[65]>(&xl[0][0]);
    bias_unit(NB1 + (blockIdx.x - 256), threadIdx.x, 384, z, lnb_w, lnb_b, wb, biasw, ob);
    return;
  }
  int r0 = blockIdx.x * 4;
  int t  = threadIdx.x;
  int ct = t % 96;
  int rg = t / 96;
  int c0 = ct * 4;
  #pragma unroll
  for (int rr = 0; rr < 4; ++rr)
    xl[rr][t] = X[(size_t)(r0+rr)*CS + t];
  __syncthreads();
  float acc1[4] = {0.f,0.f,0.f,0.f};
  float acc2[4] = {0.f,0.f,0.f,0.f};
  for (int k = 0; k < CS; k += 4){
    floatx4 s4 = *(const floatx4*)&xl[rg][k];
    #pragma unroll
    for (int kk = 0; kk < 4; ++kk){
      floatx4 w1 = *(const floatx4*)&W1[(size_t)(k+kk)*CS + c0];
      floatx4 w2 = *(const floatx4*)&W2[(size_t)(k+kk)*CS + c0];
      #pragma unroll
      for (int cc = 0; cc < 4; ++cc){
        acc1[cc] += s4[kk] * w1[cc];
        acc2[cc] += s4[kk] * w2[cc];
      }
    }
  }
  size_t obk = (size_t)(r0+rg) * CS + c0;
  #pragma unroll
  for (int cc = 0; cc < 4; ++cc)
    OUT[obk+cc] = sigmoidf_(acc1[cc] + B1[c0+cc]) * extra[obk+cc] + acc2[cc];
}

// ---------------- K3: fused q/k/v/g gemm (4 mats, one X) + bias slice ----------------
#define NB3 6656
__global__ __launch_bounds__(384) void qkvg_bias_kernel(
    const float* __restrict__ X,
    const float* __restrict__ wq, const float* __restrict__ bq,
    const float* __restrict__ wk, const float* __restrict__ wv,
    const float* __restrict__ wg,
    float* __restrict__ qo, float* __restrict__ ko,
    float* __restrict__ vo, float* __restrict__ go,
    const float* __restrict__ z, const float* __restrict__ lnb_w,
    const float* __restrict__ lnb_b, const float* __restrict__ wb,
    unsigned short* __restrict__ biasw)
{
  __shared__ float xl[4][CS];
  if (blockIdx.x >= 256){
    float (*ob)[65] = reinterpret_cast<float(*)[65]>(&xl[0][0]);
    bias_unit(NB1 + NB2 + (blockIdx.x - 256), threadIdx.x, 384, z, lnb_w, lnb_b, wb, biasw, ob);
    return;
  }
  int r0 = blockIdx.x * 4;
  int t  = threadIdx.x;
  int ct = t % 96;
  int rg = t / 96;
  int c0 = ct * 4;
  #pragma unroll
  for (int rr = 0; rr < 4; ++rr)
    xl[rr][t] = X[(size_t)(r0+rr)*CS + t];
  __syncthreads();
  float aq[4] = {0.f,0.f,0.f,0.f};
  float ak[4] = {0.f,0.f,0.f,0.f};
  float av4[4] = {0.f,0.f,0.f,0.f};
  float ag[4] = {0.f,0.f,0.f,0.f};
  for (int k = 0; k < CS; k += 4){
    floatx4 s4 = *(const floatx4*)&xl[rg][k];
    #pragma unroll
    for (int kk = 0; kk < 4; ++kk){
      floatx4 wq4 = *(const floatx4*)&wq[(size_t)(k+kk)*HC + c0];
      floatx4 wk4 = *(const floatx4*)&wk[(size_t)(k+kk)*HC + c0];
      floatx4 wv4 = *(const floatx4*)&wv[(size_t)(k+kk)*HC + c0];
      floatx4 wg4 = *(const floatx4*)&wg[(size_t)(k+kk)*HC + c0];
      #pragma unroll
      for (int cc = 0; cc < 4; ++cc){
        aq[cc]  += s4[kk] * wq4[cc];
        ak[cc]  += s4[kk] * wk4[cc];
        av4[cc] += s4[kk] * wv4[cc];
        ag[cc]  += s4[kk] * wg4[cc];
      }
    }
  }
  size_t obk = (size_t)(r0+rg) * HC + c0;
  #pragma unroll
  for (int cc = 0; cc < 4; ++cc){
    qo[obk+cc] = aq[cc] + bq[c0+cc];
    ko[obk+cc] = ak[cc];
    vo[obk+cc] = av4[cc];
    go[obk+cc] = sigmoidf_(ag[cc]);
  }
}

// ---------------- K4: fused attention (unchanged) ----------------
#define TJ 128
#define KROW 20  // uint words per LDS row (12 used, pad breaks 4-way bank conflicts)
__global__ __launch_bounds__(256) void attn_kernel(
    const float* __restrict__ qq, const float* __restrict__ kk,
    const float* __restrict__ vv, const float* __restrict__ gg,
    const unsigned short* __restrict__ bias, float* __restrict__ att)
{
  int h  = blockIdx.x & 15;
  int i0 = (blockIdx.x >> 4) * 16;
  int il = threadIdx.x & 15;
  int jg = threadIdx.x >> 4;

  __shared__ unsigned int smem[TJ*KROW*2];

  float qr[24];
  {
    const float* qs = qq + (size_t)(i0+il)*CS + h*CH;
    #pragma unroll
    for (int e = 0; e < 6; ++e){
      floatx4 t4 = *(const floatx4*)(qs + 4*e);
      qr[4*e] = t4[0]; qr[4*e+1] = t4[1]; qr[4*e+2] = t4[2]; qr[4*e+3] = t4[3];
    }
  }
  const float scale = 0.20412414523193154f; // 1/sqrt(24)
  float lrun = 0.f;
  float o[24];
  #pragma unroll
  for (int d = 0; d < 24; ++d) o[d] = 0.f;

  for (int jt = 0; jt < 8; ++jt){
    __syncthreads();
    {
      int row  = threadIdx.x >> 1;
      int half = threadIdx.x & 1;
      const float* ks = kk + (size_t)(jt*TJ + row)*CS + h*CH + half*12;
      const float* vs = vv + (size_t)(jt*TJ + row)*CS + h*CH + half*12;
      unsigned int* kd = smem + row*KROW + half*6;
      unsigned int* vd = smem + TJ*KROW + row*KROW + half*6;
      #pragma unroll
      for (int e = 0; e < 6; ++e){
        kd[e] = (unsigned)f2bf(ks[2*e]) | ((unsigned)f2bf(ks[2*e+1]) << 16);
        vd[e] = (unsigned)f2bf(vs[2*e]) | ((unsigned)f2bf(vs[2*e+1]) << 16);
      }
    }
    __syncthreads();
    const unsigned short* bptr = bias + (size_t)h*((size_t)N_SEQ*N_SEQ)
                               + (size_t)(i0+il)*N_SEQ + jt*TJ;
    #pragma unroll
    for (int tt = 0; tt < 8; ++tt){
      int jl = jg + 16*tt;
      uintx4 k0 = *(const uintx4*)&smem[jl*KROW];
      uintx4 k1 = *(const uintx4*)&smem[jl*KROW + 4];
      uintx4 k2 = *(const uintx4*)&smem[jl*KROW + 8];
      float dot = 0.f;
      #pragma unroll
      for (int e = 0; e < 4; ++e){
        dot += bf_lo(k0[e])*qr[2*e]      + bf_hi(k0[e])*qr[2*e+1];
        dot += bf_lo(k1[e])*qr[8+2*e]    + bf_hi(k1[e])*qr[8+2*e+1];
        dot += bf_lo(k2[e])*qr[16+2*e]   + bf_hi(k2[e])*qr[16+2*e+1];
      }
      float p = __expf(dot * scale + bf2f(bptr[jl]));
      lrun += p;
      uintx4 v0 = *(const uintx4*)&smem[TJ*KROW + jl*KROW];
      uintx4 v1 = *(const uintx4*)&smem[TJ*KROW + jl*KROW + 4];
      uintx4 v2 = *(const uintx4*)&smem[TJ*KROW + jl*KROW + 8];
      #pragma unroll
      for (int e = 0; e < 4; ++e){
        o[2*e]      += p * bf_lo(v0[e]);  o[2*e+1]    += p * bf_hi(v0[e]);
        o[8+2*e]    += p * bf_lo(v1[e]);  o[8+2*e+1]  += p * bf_hi(v1[e]);
        o[16+2*e]   += p * bf_lo(v2[e]);  o[16+2*e+1] += p * bf_hi(v2[e]);
      }
    }
  }
  __syncthreads();
  #pragma unroll
  for (int d = 0; d < 24; ++d){
    o[d] += __shfl_xor(o[d], 16);
    o[d] += __shfl_xor(o[d], 32);
  }
  lrun += __shfl_xor(lrun, 16);
  lrun += __shfl_xor(lrun, 32);
  float* mgf = (float*)smem;
  int lane = threadIdx.x & 63;
  int w    = threadIdx.x >> 6;
  if (lane < 16){
    float* slot = mgf + (w*16 + lane)*25;
    slot[0] = lrun;
    #pragma unroll
    for (int d = 0; d < 24; ++d) slot[1+d] = o[d];
  }
  __syncthreads();
  if (threadIdx.x < 16){
    int ii = threadIdx.x;
    float L = 0.f, O[24];
    #pragma unroll
    for (int d = 0; d < 24; ++d) O[d] = 0.f;
    for (int w2 = 0; w2 < 4; ++w2){
      const float* slot = mgf + (w2*16 + ii)*25;
      L += slot[0];
      #pragma unroll
      for (int d = 0; d < 24; ++d) O[d] += slot[1+d];
    }
    const float* gs = gg + (size_t)(i0+ii)*CS + h*CH;
    float* os = att + (size_t)(i0+ii)*CS + h*CH;
    float invL = 1.f / L;
    #pragma unroll
    for (int d = 0; d < 24; ++d) os[d] = O[d] * invL * gs[d];
  }
}

// ---------------- K5: out-projection + final gate, fused dual-X gemm ----------------
__global__ __launch_bounds__(384) void out_final_kernel(
    const float* __restrict__ attb, const float* __restrict__ wo,
    const float* __restrict__ s_i,  const float* __restrict__ wsm,
    const float* __restrict__ bsv,  float* __restrict__ out)
{
  __shared__ float xo[4][CS];
  __shared__ float xs[4][CS];
  int r0 = blockIdx.x * 4;
  int t  = threadIdx.x;
  int ct = t % 96;
  int rg = t / 96;
  int c0 = ct * 4;
  #pragma unroll
  for (int rr = 0; rr < 4; ++rr){
    xo[rr][t] = attb[(size_t)(r0+rr)*CS + t];
    xs[rr][t] = s_i [(size_t)(r0+rr)*CS + t];
  }
  __syncthreads();
  float ao[4] = {0.f,0.f,0.f,0.f};
  float as[4] = {0.f,0.f,0.f,0.f};
  for (int k = 0; k < CS; k += 4){
    floatx4 o4 = *(const floatx4*)&xo[rg][k];
    floatx4 s4 = *(const floatx4*)&xs[rg][k];
    #pragma unroll
    for (int kk = 0; kk < 4; ++kk){
      floatx4 w1 = *(const floatx4*)&wo [(size_t)(k+kk)*CS + c0];
      floatx4 w2 = *(const floatx4*)&wsm[(size_t)(k+kk)*CS + c0];
      #pragma unroll
      for (int cc = 0; cc < 4; ++cc){
        ao[cc] += o4[kk] * w1[cc];
        as[cc] += s4[kk] * w2[cc];
      }
    }
  }
  size_t obk = (size_t)(r0+rg) * CS + c0;
  #pragma unroll
  for (int cc = 0; cc < 4; ++cc)
    out[obk+cc] = sigmoidf_(as[cc] + bsv[c0+cc]) * ao[cc];
}

extern "C" void kernel_launch(void* const* d_in, const int* in_sizes, int n_in,
                              void* d_out, int out_size, void* d_ws, size_t ws_size,
                              hipStream_t stream) {
  const float* a_i     = (const float*)d_in[0];
  const float* s_i     = (const float*)d_in[1];
  const float* z_ij    = (const float*)d_in[2];
  const float* lns_w   = (const float*)d_in[3];
  const float* ada_ws  = (const float*)d_in[4];
  const float* ada_bs  = (const float*)d_in[5];
  const float* ada_wns = (const float*)d_in[6];
  const float* wq      = (const float*)d_in[7];
  const float* bq      = (const float*)d_in[8];
  const float* wk      = (const float*)d_in[9];
  const float* wv      = (const float*)d_in[10];
  const float* lnb_w   = (const float*)d_in[11];
  const float* lnb_b   = (const float*)d_in[12];
  const float* wb      = (const float*)d_in[13];
  const float* wg      = (const float*)d_in[14];
  const float* wo      = (const float*)d_in[15];
  const float* wsm     = (const float*)d_in[16];
  const float* bsv     = (const float*)d_in[17];

  const size_t RC = (size_t)N_SEQ * CS;   // 393216
  float* wsf  = (float*)d_ws;
  float* s_ln = wsf;
  float* a_ln = wsf + RC;
  float* a    = wsf + 2*RC;
  float* qv   = wsf + 3*RC;
  float* kv   = wsf + 4*RC;
  float* vvp  = wsf + 5*RC;
  float* gv   = wsf + 6*RC;
  float* attb = wsf + 7*RC;
  unsigned short* biasw = (unsigned short*)(wsf + 9*RC);  // 32 MB bf16

  ln_bias_kernel<<<LN_BLOCKS + NB1, 256, 0, stream>>>(
      a_i, s_i, lns_w, a_ln, s_ln, z_ij, lnb_w, lnb_b, wb, biasw);
  adaln_bias_kernel<<<256 + NB2, 384, 0, stream>>>(
      s_ln, ada_ws, ada_bs, ada_wns, a_ln, a, z_ij, lnb_w, lnb_b, wb, biasw);
  qkvg_bias_kernel<<<256 + NB3, 384, 0, stream>>>(
      a, wq, bq, wk, wv, wg, qv, kv, vvp, gv, z_ij, lnb_w, lnb_b, wb, biasw);
  attn_kernel<<<N_SEQ, 256, 0, stream>>>(qv, kv, vvp, gv, biasw, attb);
  out_final_kernel<<<256, 384, 0, stream>>>(attb, wo, s_i, wsm, bsv, (float*)d_out);
}

// Round 2
// 1037.975 us; speedup vs baseline: 1.1284x; 1.0215x over previous
//
#include <hip/hip_runtime.h>
#include <hip/hip_bf16.h>
#include <math.h>

#define N_SEQ 1024
#define CS 384
#define CZ 128
#define NH 16
#define CH 24
#define HC 384

typedef float  floatx4 __attribute__((ext_vector_type(4)));
typedef short  shortx8 __attribute__((ext_vector_type(8)));
typedef unsigned int uintx4 __attribute__((ext_vector_type(4)));

__device__ __forceinline__ unsigned short f2bf(float f){
  union { float fv; unsigned u; } c; c.fv = f;
  unsigned u = c.u;
  return (unsigned short)((u + 0x7fffu + ((u >> 16) & 1u)) >> 16);
}
__device__ __forceinline__ float bf2f(unsigned short s){
  union { unsigned u; float fv; } c; c.u = ((unsigned)s) << 16; return c.fv;
}
__device__ __forceinline__ float bf_lo(unsigned u){
  union { unsigned uu; float f; } c; c.uu = u << 16; return c.f;
}
__device__ __forceinline__ float bf_hi(unsigned u){
  union { unsigned uu; float f; } c; c.uu = u & 0xffff0000u; return c.f;
}
__device__ __forceinline__ unsigned pack2(float lo, float hi){
  return (unsigned)f2bf(lo) | ((unsigned)f2bf(hi) << 16);
}
__device__ __forceinline__ float sigmoidf_(float x){ return 1.f / (1.f + __expf(-x)); }

// ---------------- bias unit: one tile (i, j0..j0+63) of the pair-bias tensor.
// Works with nthr = 256 or 384. ob must point to >= 16*65 floats of LDS.
__device__ __forceinline__ void bias_unit(int u, int tid, int nthr,
    const float* __restrict__ z, const float* __restrict__ lnb_w,
    const float* __restrict__ lnb_b, const float* __restrict__ wb,
    unsigned short* __restrict__ bias, float (*ob)[65])
{
  int i    = u >> 4;
  int j0   = (u & 15) * 64;
  int wave = tid >> 6;
  int lane = tid & 63;

  if (wave < 4){
    int m = lane & 15;   // A-row (pair) for loads; also D-col (head) in epilogue
    int q = lane >> 4;   // quad
    int jbase = j0 + wave * 16;

    shortx8 bfrag[4];
    float sumw = 0.f, sumb = 0.f;
    #pragma unroll
    for (int s = 0; s < 4; ++s){
      #pragma unroll
      for (int jj = 0; jj < 8; ++jj){
        int c = q*8 + jj + 32*s;
        float lw = lnb_w[c];
        float lb = lnb_b[c];
        float w  = wb[c*NH + m];
        bfrag[s][jj] = (short)f2bf(lw * w);
        sumw += lw * w;
        sumb += lb * w;
      }
    }
    sumw += __shfl_xor(sumw, 16); sumw += __shfl_xor(sumw, 32);
    sumb += __shfl_xor(sumb, 16); sumb += __shfl_xor(sumb, 32);

    const float* zrow = z + ((size_t)i * N_SEQ + (size_t)(jbase + m)) * CZ;
    floatx4 acc = {0.f, 0.f, 0.f, 0.f};
    float sum = 0.f, sq = 0.f;
    #pragma unroll
    for (int s = 0; s < 4; ++s){
      floatx4 z0 = *(const floatx4*)(zrow + q*8 + 32*s);
      floatx4 z1 = *(const floatx4*)(zrow + q*8 + 32*s + 4);
      shortx8 af;
      #pragma unroll
      for (int e = 0; e < 4; ++e){
        sum += z0[e]; sq += z0[e]*z0[e];
        sum += z1[e]; sq += z1[e]*z1[e];
        af[e]   = (short)f2bf(z0[e]);
        af[e+4] = (short)f2bf(z1[e]);
      }
      acc = __builtin_amdgcn_mfma_f32_16x16x32_bf16(af, bfrag[s], acc, 0, 0, 0);
    }
    sum += __shfl_xor(sum, 16); sum += __shfl_xor(sum, 32);
    sq  += __shfl_xor(sq , 16); sq  += __shfl_xor(sq , 32);
    float mean = sum * (1.f/CZ);
    float var  = sq  * (1.f/CZ) - mean*mean;
    float rstd = rsqrtf(var + 1e-5f);

    #pragma unroll
    for (int r = 0; r < 4; ++r){
      int row = q*4 + r;
      float mr = __shfl(mean, row);
      float rr = __shfl(rstd, row);
      ob[m][wave*16 + row] = rr * (acc[r] - mr * sumw) + sumb;
    }
  }
  __syncthreads();
  size_t base = (size_t)i * N_SEQ + j0;
  for (int idx = tid; idx < NH*64; idx += nthr){
    int hh = idx >> 6;
    int jj = idx & 63;
    bias[(size_t)hh * ((size_t)N_SEQ*N_SEQ) + base + jj] = f2bf(ob[hh][jj]);
  }
}

// ---------------- K_A: fused LN + AdaLN + QKVG (row-local chain) + all bias units
#define NGEMM 128
__global__ __launch_bounds__(384) void pre_kernel(
    const float* __restrict__ a_i, const float* __restrict__ s_i,
    const float* __restrict__ lns_w,
    const float* __restrict__ W1, const float* __restrict__ B1,
    const float* __restrict__ W2,
    const float* __restrict__ wq, const float* __restrict__ bq,
    const float* __restrict__ wk, const float* __restrict__ wv,
    const float* __restrict__ wg,
    float* __restrict__ qo, float* __restrict__ ko,
    float* __restrict__ vo, float* __restrict__ go,
    const float* __restrict__ z, const float* __restrict__ lnb_w,
    const float* __restrict__ lnb_b, const float* __restrict__ wb,
    unsigned short* __restrict__ biasw)
{
  __shared__ float tileA[8][CS];   // a_ln, then AdaLN output (in-place, owner cells)
  __shared__ float tileS[8][CS];   // s_ln
  __shared__ float red[6][8][4];
  __shared__ float fin[8][4];
  if (blockIdx.x >= NGEMM){
    bias_unit(blockIdx.x - NGEMM, threadIdx.x, 384, z, lnb_w, lnb_b, wb, biasw,
              reinterpret_cast<float(*)[65]>(&tileA[0][0]));
    return;
  }
  int r0 = blockIdx.x * 8;
  int t  = threadIdx.x;
  // ---- LayerNorm of 8 rows of a_i and s_i ----
  float sa[8], qa[8], ss[8], qs[8];
  #pragma unroll
  for (int rr = 0; rr < 8; ++rr){
    float a = a_i[(size_t)(r0+rr)*CS + t];
    float s = s_i[(size_t)(r0+rr)*CS + t];
    tileA[rr][t] = a; tileS[rr][t] = s;
    sa[rr] = a; qa[rr] = a*a; ss[rr] = s; qs[rr] = s*s;
  }
  #pragma unroll
  for (int rr = 0; rr < 8; ++rr){
    #pragma unroll
    for (int off = 1; off < 64; off <<= 1){
      sa[rr] += __shfl_xor(sa[rr], off);
      qa[rr] += __shfl_xor(qa[rr], off);
      ss[rr] += __shfl_xor(ss[rr], off);
      qs[rr] += __shfl_xor(qs[rr], off);
    }
  }
  {
    int lane = t & 63, w = t >> 6;
    if (lane == 0){
      #pragma unroll
      for (int rr = 0; rr < 8; ++rr){
        red[w][rr][0]=sa[rr]; red[w][rr][1]=qa[rr];
        red[w][rr][2]=ss[rr]; red[w][rr][3]=qs[rr];
      }
    }
  }
  __syncthreads();
  if (t < 8){
    float Sa=0.f,Qa=0.f,Ss=0.f,Qs=0.f;
    #pragma unroll
    for (int w=0; w<6; ++w){
      Sa+=red[w][t][0]; Qa+=red[w][t][1]; Ss+=red[w][t][2]; Qs+=red[w][t][3];
    }
    const float inv = 1.f/CS;
    float ma=Sa*inv, va=Qa*inv-ma*ma;
    float ms=Ss*inv, vs=Qs*inv-ms*ms;
    fin[t][0]=ma; fin[t][1]=rsqrtf(va+1e-5f);
    fin[t][2]=ms; fin[t][3]=rsqrtf(vs+1e-5f);
  }
  __syncthreads();
  {
    float lw = lns_w[t];
    #pragma unroll
    for (int rr = 0; rr < 8; ++rr){
      tileA[rr][t] = (tileA[rr][t]-fin[rr][0])*fin[rr][1];
      tileS[rr][t] = (tileS[rr][t]-fin[rr][2])*fin[rr][3]*lw;
    }
  }
  __syncthreads();
  // ---- AdaLN: a = sigmoid(s_ln@W1 + B1) * a_ln + s_ln@W2 ----
  int ct = t % 96, rgg = t / 96, c0 = ct*4;
  {
    float A1[2][4]={{0.f}}, A2[2][4]={{0.f}};
    for (int k=0;k<CS;k+=4){
      floatx4 xa = *(const floatx4*)&tileS[rgg][k];
      floatx4 xb = *(const floatx4*)&tileS[rgg+4][k];
      #pragma unroll
      for (int kk=0;kk<4;++kk){
        floatx4 w1 = *(const floatx4*)&W1[(size_t)(k+kk)*CS + c0];
        floatx4 w2 = *(const floatx4*)&W2[(size_t)(k+kk)*CS + c0];
        #pragma unroll
        for (int cc=0;cc<4;++cc){
          A1[0][cc] += xa[kk]*w1[cc];  A1[1][cc] += xb[kk]*w1[cc];
          A2[0][cc] += xa[kk]*w2[cc];  A2[1][cc] += xb[kk]*w2[cc];
        }
      }
    }
    // only the owning thread ever touches tileA[rr][c0..c0+3] -> no barrier needed
    #pragma unroll
    for (int r2=0;r2<2;++r2){
      int rr = rgg + 4*r2;
      #pragma unroll
      for (int cc=0;cc<4;++cc){
        float g = sigmoidf_(A1[r2][cc] + B1[c0+cc]);
        tileA[rr][c0+cc] = g * tileA[rr][c0+cc] + A2[r2][cc];
      }
    }
  }
  __syncthreads();
  // ---- QKVG: 4 matrices from tileA ----
  {
    float AQ[2][4]={{0.f}}, AK[2][4]={{0.f}}, AV[2][4]={{0.f}}, AG[2][4]={{0.f}};
    for (int k=0;k<CS;k+=4){
      floatx4 xa = *(const floatx4*)&tileA[rgg][k];
      floatx4 xb = *(const floatx4*)&tileA[rgg+4][k];
      #pragma unroll
      for (int kk=0;kk<4;++kk){
        floatx4 q4 = *(const floatx4*)&wq[(size_t)(k+kk)*HC + c0];
        floatx4 k4 = *(const floatx4*)&wk[(size_t)(k+kk)*HC + c0];
        floatx4 v4 = *(const floatx4*)&wv[(size_t)(k+kk)*HC + c0];
        floatx4 g4 = *(const floatx4*)&wg[(size_t)(k+kk)*HC + c0];
        #pragma unroll
        for (int cc=0;cc<4;++cc){
          AQ[0][cc]+=xa[kk]*q4[cc]; AQ[1][cc]+=xb[kk]*q4[cc];
          AK[0][cc]+=xa[kk]*k4[cc]; AK[1][cc]+=xb[kk]*k4[cc];
          AV[0][cc]+=xa[kk]*v4[cc]; AV[1][cc]+=xb[kk]*v4[cc];
          AG[0][cc]+=xa[kk]*g4[cc]; AG[1][cc]+=xb[kk]*g4[cc];
        }
      }
    }
    #pragma unroll
    for (int r2=0;r2<2;++r2){
      size_t ob = (size_t)(r0 + rgg + 4*r2)*HC + c0;
      #pragma unroll
      for (int cc=0;cc<4;++cc){
        qo[ob+cc] = AQ[r2][cc] + bq[c0+cc];
        ko[ob+cc] = AK[r2][cc];
        vo[ob+cc] = AV[r2][cc];
        go[ob+cc] = sigmoidf_(AG[r2][cc]);
      }
    }
  }
}

// ---------------- K_B: fused attention ----------------
#define TJ 128
#define KROW 20  // uint words per LDS row (12 used, pad breaks 4-way bank conflicts)
__global__ __launch_bounds__(256) void attn_kernel(
    const float* __restrict__ qq, const float* __restrict__ kk,
    const float* __restrict__ vv, const float* __restrict__ gg,
    const unsigned short* __restrict__ bias, float* __restrict__ att)
{
  int h  = blockIdx.x & 15;
  int i0 = (blockIdx.x >> 4) * 16;
  int il = threadIdx.x & 15;
  int jg = threadIdx.x >> 4;

  __shared__ unsigned int smem[TJ*KROW*2];

  float qr[24];
  {
    const float* qs = qq + (size_t)(i0+il)*CS + h*CH;
    #pragma unroll
    for (int e = 0; e < 6; ++e){
      floatx4 t4 = *(const floatx4*)(qs + 4*e);
      qr[4*e] = t4[0]; qr[4*e+1] = t4[1]; qr[4*e+2] = t4[2]; qr[4*e+3] = t4[3];
    }
  }
  const float scale = 0.20412414523193154f; // 1/sqrt(24)
  float lrun = 0.f;
  float o[24];
  #pragma unroll
  for (int d = 0; d < 24; ++d) o[d] = 0.f;

  for (int jt = 0; jt < 8; ++jt){
    __syncthreads();
    {
      int row  = threadIdx.x >> 1;
      int half = threadIdx.x & 1;
      const float* ks = kk + (size_t)(jt*TJ + row)*CS + h*CH + half*12;
      const float* vs = vv + (size_t)(jt*TJ + row)*CS + h*CH + half*12;
      floatx4 a0 = *(const floatx4*)(ks);
      floatx4 a1 = *(const floatx4*)(ks+4);
      floatx4 a2 = *(const floatx4*)(ks+8);
      floatx4 b0 = *(const floatx4*)(vs);
      floatx4 b1 = *(const floatx4*)(vs+4);
      floatx4 b2 = *(const floatx4*)(vs+8);
      unsigned int* kd = smem + row*KROW + half*6;
      unsigned int* vd = smem + TJ*KROW + row*KROW + half*6;
      kd[0]=pack2(a0[0],a0[1]); kd[1]=pack2(a0[2],a0[3]);
      kd[2]=pack2(a1[0],a1[1]); kd[3]=pack2(a1[2],a1[3]);
      kd[4]=pack2(a2[0],a2[1]); kd[5]=pack2(a2[2],a2[3]);
      vd[0]=pack2(b0[0],b0[1]); vd[1]=pack2(b0[2],b0[3]);
      vd[2]=pack2(b1[0],b1[1]); vd[3]=pack2(b1[2],b1[3]);
      vd[4]=pack2(b2[0],b2[1]); vd[5]=pack2(b2[2],b2[3]);
    }
    __syncthreads();
    const unsigned short* bptr = bias + (size_t)h*((size_t)N_SEQ*N_SEQ)
                               + (size_t)(i0+il)*N_SEQ + jt*TJ;
    #pragma unroll
    for (int tt = 0; tt < 8; ++tt){
      int jl = jg + 16*tt;
      uintx4 k0 = *(const uintx4*)&smem[jl*KROW];
      uintx4 k1 = *(const uintx4*)&smem[jl*KROW + 4];
      uintx4 k2 = *(const uintx4*)&smem[jl*KROW + 8];
      float dot = 0.f;
      #pragma unroll
      for (int e = 0; e < 4; ++e){
        dot += bf_lo(k0[e])*qr[2*e]      + bf_hi(k0[e])*qr[2*e+1];
        dot += bf_lo(k1[e])*qr[8+2*e]    + bf_hi(k1[e])*qr[8+2*e+1];
        dot += bf_lo(k2[e])*qr[16+2*e]   + bf_hi(k2[e])*qr[16+2*e+1];
      }
      float p = __expf(dot * scale + bf2f(bptr[jl]));
      lrun += p;
      uintx4 v0 = *(const uintx4*)&smem[TJ*KROW + jl*KROW];
      uintx4 v1 = *(const uintx4*)&smem[TJ*KROW + jl*KROW + 4];
      uintx4 v2 = *(const uintx4*)&smem[TJ*KROW + jl*KROW + 8];
      #pragma unroll
      for (int e = 0; e < 4; ++e){
        o[2*e]      += p * bf_lo(v0[e]);  o[2*e+1]    += p * bf_hi(v0[e]);
        o[8+2*e]    += p * bf_lo(v1[e]);  o[8+2*e+1]  += p * bf_hi(v1[e]);
        o[16+2*e]   += p * bf_lo(v2[e]);  o[16+2*e+1] += p * bf_hi(v2[e]);
      }
    }
  }
  __syncthreads();
  #pragma unroll
  for (int d = 0; d < 24; ++d){
    o[d] += __shfl_xor(o[d], 16);
    o[d] += __shfl_xor(o[d], 32);
  }
  lrun += __shfl_xor(lrun, 16);
  lrun += __shfl_xor(lrun, 32);
  float* mgf = (float*)smem;
  int lane = threadIdx.x & 63;
  int w    = threadIdx.x >> 6;
  if (lane < 16){
    float* slot = mgf + (w*16 + lane)*25;
    slot[0] = lrun;
    #pragma unroll
    for (int d = 0; d < 24; ++d) slot[1+d] = o[d];
  }
  __syncthreads();
  if (threadIdx.x < 16){
    int ii = threadIdx.x;
    float L = 0.f, O[24];
    #pragma unroll
    for (int d = 0; d < 24; ++d) O[d] = 0.f;
    for (int w2 = 0; w2 < 4; ++w2){
      const float* slot = mgf + (w2*16 + ii)*25;
      L += slot[0];
      #pragma unroll
      for (int d = 0; d < 24; ++d) O[d] += slot[1+d];
    }
    const float* gs = gg + (size_t)(i0+ii)*CS + h*CH;
    float* os = att + (size_t)(i0+ii)*CS + h*CH;
    float invL = 1.f / L;
    #pragma unroll
    for (int d = 0; d < 24; ++d) os[d] = O[d] * invL * gs[d];
  }
}

// ---------------- K_C: out-projection + final gate (8 rows/block) ----------------
__global__ __launch_bounds__(384) void out_final_kernel(
    const float* __restrict__ attb, const float* __restrict__ wo,
    const float* __restrict__ s_i,  const float* __restrict__ wsm,
    const float* __restrict__ bsv,  float* __restrict__ out)
{
  __shared__ float xo[8][CS];
  __shared__ float xs[8][CS];
  int r0 = blockIdx.x * 8;
  int t  = threadIdx.x;
  #pragma unroll
  for (int rr = 0; rr < 8; ++rr){
    xo[rr][t] = attb[(size_t)(r0+rr)*CS + t];
    xs[rr][t] = s_i [(size_t)(r0+rr)*CS + t];
  }
  __syncthreads();
  int ct = t % 96, rgg = t / 96, c0 = ct*4;
  float AO[2][4]={{0.f}}, AS[2][4]={{0.f}};
  for (int k=0;k<CS;k+=4){
    floatx4 oa = *(const floatx4*)&xo[rgg][k];
    floatx4 ob4 = *(const floatx4*)&xo[rgg+4][k];
    floatx4 sa4 = *(const floatx4*)&xs[rgg][k];
    floatx4 sb4 = *(const floatx4*)&xs[rgg+4][k];
    #pragma unroll
    for (int kk=0;kk<4;++kk){
      floatx4 w1 = *(const floatx4*)&wo [(size_t)(k+kk)*CS + c0];
      floatx4 w2 = *(const floatx4*)&wsm[(size_t)(k+kk)*CS + c0];
      #pragma unroll
      for (int cc=0;cc<4;++cc){
        AO[0][cc] += oa[kk]*w1[cc];  AO[1][cc] += ob4[kk]*w1[cc];
        AS[0][cc] += sa4[kk]*w2[cc]; AS[1][cc] += sb4[kk]*w2[cc];
      }
    }
  }
  #pragma unroll
  for (int r2=0;r2<2;++r2){
    size_t ob = (size_t)(r0 + rgg + 4*r2)*CS + c0;
    #pragma unroll
    for (int cc=0;cc<4;++cc)
      out[ob+cc] = sigmoidf_(AS[r2][cc] + bsv[c0+cc]) * AO[r2][cc];
  }
}

extern "C" void kernel_launch(void* const* d_in, const int* in_sizes, int n_in,
                              void* d_out, int out_size, void* d_ws, size_t ws_size,
                              hipStream_t stream) {
  const float* a_i     = (const float*)d_in[0];
  const float* s_i     = (const float*)d_in[1];
  const float* z_ij    = (const float*)d_in[2];
  const float* lns_w   = (const float*)d_in[3];
  const float* ada_ws  = (const float*)d_in[4];
  const float* ada_bs  = (const float*)d_in[5];
  const float* ada_wns = (const float*)d_in[6];
  const float* wq      = (const float*)d_in[7];
  const float* bq      = (const float*)d_in[8];
  const float* wk      = (const float*)d_in[9];
  const float* wv      = (const float*)d_in[10];
  const float* lnb_w   = (const float*)d_in[11];
  const float* lnb_b   = (const float*)d_in[12];
  const float* wb      = (const float*)d_in[13];
  const float* wg      = (const float*)d_in[14];
  const float* wo      = (const float*)d_in[15];
  const float* wsm     = (const float*)d_in[16];
  const float* bsv     = (const float*)d_in[17];

  const size_t RC = (size_t)N_SEQ * CS;   // 393216
  float* wsf  = (float*)d_ws;
  float* qv   = wsf + 3*RC;
  float* kv   = wsf + 4*RC;
  float* vvp  = wsf + 5*RC;
  float* gv   = wsf + 6*RC;
  float* attb = wsf + 7*RC;
  unsigned short* biasw = (unsigned short*)(wsf + 9*RC);  // 32 MB bf16

  pre_kernel<<<NGEMM + N_SEQ*16, 384, 0, stream>>>(
      a_i, s_i, lns_w, ada_ws, ada_bs, ada_wns,
      wq, bq, wk, wv, wg, qv, kv, vvp, gv,
      z_ij, lnb_w, lnb_b, wb, biasw);
  attn_kernel<<<N_SEQ, 256, 0, stream>>>(qv, kv, vvp, gv, biasw, attb);
  out_final_kernel<<<N_SEQ/8, 384, 0, stream>>>(attb, wo, s_i, wsm, bsv, (float*)d_out);
}